// Round 3
// baseline (2486.822 us; speedup 1.0000x reference)
//
#include <hip/hip_runtime.h>
#include <hip/hip_bf16.h>

// Problem constants
#define NB   64      // batch
#define NTOK 4096    // N tokens
#define NS   16      // K slots
#define DD   256     // DIN == DOUT
#define HID_ 512
#define LN_EPS 1e-5f

typedef __attribute__((ext_vector_type(8))) short short8;   // 8 bf16 (4 VGPRs)
typedef __attribute__((ext_vector_type(4))) float f32x4;    // MFMA C/D frag

__device__ __forceinline__ ushort f2bf(float f) {
    __hip_bfloat16 h = __float2bfloat16(f);
    return *reinterpret_cast<ushort*>(&h);
}
__device__ __forceinline__ float bf2f(ushort u) {
    union { float f; unsigned int i; } c; c.i = ((unsigned int)u) << 16; return c.f;
}

// ---------------- init: slots0 = mu + exp(logsigma)*slots_init; zero LN0 sums --------
__global__ void kinit(const float* __restrict__ slots_init, const float* __restrict__ mu,
                      const float* __restrict__ logsig, float* __restrict__ slots,
                      float* __restrict__ sums) {
    int i = blockIdx.x * 256 + threadIdx.x;    // 262144 exactly
    int d = i & 255;
    slots[i] = mu[d] + __expf(logsig[d]) * slots_init[i];
    if (blockIdx.x == 0 && threadIdx.x < 128) sums[threadIdx.x] = 0.f;
}

// ---------------- MFMA B-frag swizzles for kW/vW (bf16) -----------------------------
// kw_sw/vw_sw [it][ds(8)][Et(16)][lane(64)][j(8)]: B[k=d][n=e], d=ds*32+(lane>>4)*8+j, e=Et*16+(lane&15)
__global__ void kprep2(const float* __restrict__ kW, const float* __restrict__ vW,
                       ushort* __restrict__ kw_sw, ushort* __restrict__ vw_sw) {
    int li = blockIdx.x * 256 + threadIdx.x;   // 393,216 exactly
    const float* src = kW; ushort* dst = kw_sw;
    if (li >= 196608) { li -= 196608; src = vW; dst = vw_sw; }
    int it = li / 65536, r = li % 65536;
    int ds = r >> 13, r2 = r & 8191;
    int Et = r2 >> 9, r3 = r2 & 511;
    int ln = r3 >> 3, j = r3 & 7;
    int d = ds * 32 + (ln >> 4) * 8 + j;
    int e = Et * 16 + (ln & 15);
    dst[li] = f2bf(src[it * 65536 + e * 256 + d]);
}

// ---------------- tiled 64x64 transposes for qWT/m1WT/m2WT (coalesced both sides) ---
// blocks 0..47: qW[it][256x256] -> qWT; 48..143: m1W[it][512x256] -> m1WT[256x512];
// 144..239: m2W[it][256x512] -> m2WT[512x256]
__global__ void ktrans(const float* __restrict__ qW, const float* __restrict__ m1W,
                       const float* __restrict__ m2W, float* __restrict__ qWT,
                       float* __restrict__ m1WT, float* __restrict__ m2WT) {
    __shared__ float tile[64][65];
    int blk = blockIdx.x, t = threadIdx.x;
    const float* src; float* dst; int R, C, tr, tc;
    if (blk < 48) {
        int it = blk >> 4, rem = blk & 15;
        R = 256; C = 256; tr = rem >> 2; tc = rem & 3;
        src = qW + it * 65536; dst = qWT + it * 65536;
    } else if (blk < 144) {
        int li = blk - 48; int it = li >> 5, rem = li & 31;
        R = 512; C = 256; tr = rem >> 2; tc = rem & 3;
        src = m1W + it * 131072; dst = m1WT + it * 131072;
    } else {
        int li = blk - 144; int it = li >> 5, rem = li & 31;
        R = 256; C = 512; tr = rem >> 3; tc = rem & 7;
        src = m2W + it * 131072; dst = m2WT + it * 131072;
    }
    int col = t & 63, rq = t >> 6;
    #pragma unroll
    for (int r = 0; r < 16; r++) {
        int row = r * 4 + rq;
        tile[row][col] = src[(tr * 64 + row) * C + tc * 64 + col];
    }
    __syncthreads();
    #pragma unroll
    for (int r = 0; r < 16; r++) {
        int row = r * 4 + rq;
        dst[(tc * 64 + row) * R + tr * 64 + col] = tile[col][row];
    }
}

// ---------------- LN0 pass 1: per-batch sum/sumsq over N*DIN = 1M elems -------------
__global__ void l0a(const float* __restrict__ inp, float* __restrict__ sums) {
    int b = blockIdx.x >> 5, seg = blockIdx.x & 31;
    const float4* p = (const float4*)inp + (size_t)b * 262144 + seg * 8192 + threadIdx.x;
    float s = 0.f, sq = 0.f;
    #pragma unroll
    for (int k = 0; k < 32; k++) {
        float4 v = p[k * 256];
        s  += v.x + v.y + v.z + v.w;
        sq += v.x * v.x + v.y * v.y + v.z * v.z + v.w * v.w;
    }
    __shared__ float r1[256], r2[256];
    r1[threadIdx.x] = s; r2[threadIdx.x] = sq; __syncthreads();
    for (int st = 128; st > 0; st >>= 1) {
        if (threadIdx.x < st) { r1[threadIdx.x] += r1[threadIdx.x + st]; r2[threadIdx.x] += r2[threadIdx.x + st]; }
        __syncthreads();
    }
    if (threadIdx.x == 0) { atomicAdd(&sums[b], r1[0]); atomicAdd(&sums[64 + b], r2[0]); }
}

// ---------------- LN0 pass 2 (fast path): normalize + write bf16 x in A-FRAG order --
// xgs[tile16(16384)][ds(8)][lane(64)][j(8)]: element x[tile16*16 + (lane&15)][ds*32 + (lane>>4)*8 + j]
__global__ void l0bs(const float* __restrict__ inp, const float* __restrict__ ln0w,
                     const float* __restrict__ ln0b, const float* __restrict__ sums,
                     ushort* __restrict__ xgs) {
    int tid = threadIdx.x;
    int gw = blockIdx.x * 4 + (tid >> 6);      // 131072 wave tasks
    int lane = tid & 63, l15 = lane & 15, quad = lane >> 4;
    int tile16 = gw >> 3, ds = gw & 7;
    int token = tile16 * 16 + l15;             // global token (b*4096 + n)
    int b = tile16 >> 8;
    int n = token & 4095;
    int dcol = ds * 32 + quad * 8;
    float mean = sums[b] * (1.f / 1048576.f);
    float rstd = rsqrtf(sums[64 + b] * (1.f / 1048576.f) - mean * mean + LN_EPS);
    const float4* xp = (const float4*)(inp + (size_t)token * 256 + dcol);
    const float4* wp = (const float4*)(ln0w + n * 256 + dcol);
    const float4* bp = (const float4*)(ln0b + n * 256 + dcol);
    float4 v0 = xp[0], v1 = xp[1];
    float4 w0 = wp[0], w1 = wp[1];
    float4 b0 = bp[0], b1 = bp[1];
    ushort o[8];
    o[0] = f2bf((v0.x - mean) * rstd * w0.x + b0.x);
    o[1] = f2bf((v0.y - mean) * rstd * w0.y + b0.y);
    o[2] = f2bf((v0.z - mean) * rstd * w0.z + b0.z);
    o[3] = f2bf((v0.w - mean) * rstd * w0.w + b0.w);
    o[4] = f2bf((v1.x - mean) * rstd * w1.x + b1.x);
    o[5] = f2bf((v1.y - mean) * rstd * w1.y + b1.y);
    o[6] = f2bf((v1.z - mean) * rstd * w1.z + b1.z);
    o[7] = f2bf((v1.w - mean) * rstd * w1.w + b1.w);
    *(short8*)(xgs + ((size_t)gw * 64 + lane) * 8) = *(short8*)o;
}

// ---------------- per-iter small kernel: LN1(slots) -> q (scaled 1/16, bf16), q.kb, zero denom
__global__ void kq(const float* __restrict__ slots, const float* __restrict__ ln1w,
                   const float* __restrict__ ln1b, const float* __restrict__ qWT,
                   const float* __restrict__ qb, const float* __restrict__ kb,
                   ushort* __restrict__ qg, float* __restrict__ qkb, float* __restrict__ denom) {
    int b = blockIdx.x, t = threadIdx.x;
    __shared__ float sl[4096];
    __shared__ float r1[256], r2[256];
    const float* sp = slots + b * 4096;
    float vals[16]; float s = 0.f, sq = 0.f;
    #pragma unroll
    for (int k = 0; k < 16; k++) { float v = sp[k * 256 + t]; vals[k] = v; s += v; sq += v * v; }
    r1[t] = s; r2[t] = sq; __syncthreads();
    for (int st = 128; st > 0; st >>= 1) {
        if (t < st) { r1[t] += r1[t + st]; r2[t] += r2[t + st]; }
        __syncthreads();
    }
    float m  = r1[0] * (1.f / 4096.f);
    float rs = rsqrtf(r2[0] * (1.f / 4096.f) - m * m + LN_EPS);
    #pragma unroll
    for (int k = 0; k < 16; k++)
        sl[k * 256 + t] = (vals[k] - m) * rs * ln1w[k * 256 + t] + ln1b[k * 256 + t];
    __syncthreads();
    float acc[16];
    #pragma unroll
    for (int k = 0; k < 16; k++) acc[k] = 0.f;
    for (int d = 0; d < 256; d++) {
        float wv = qWT[d * 256 + t];
        #pragma unroll
        for (int k = 0; k < 16; k++) acc[k] += sl[k * 256 + d] * wv;
    }
    __syncthreads();   // done reading sl as s~
    float qbv = qb[t];
    #pragma unroll
    for (int k = 0; k < 16; k++) {
        float qv = (acc[k] + qbv) * (1.f / 16.f);   // fold dist /K here
        sl[k * 256 + t] = qv;
        qg[(b * 16 + k) * 256 + t] = f2bf(qv);
    }
    __syncthreads();
    if (t < 16) {
        float kbs = 0.f;
        for (int e = 0; e < 256; e++) kbs += sl[t * 256 + e] * kb[e];
        qkb[b * 16 + t] = kbs;
    } else if (t < 32) {
        denom[b * 16 + (t - 16)] = 0.f;
    }
}

// ---------------- FAST fused kernel: k/v proj + dist + softmax + PV ------------------
// Reads pre-LN'd bf16 x directly from global in A-frag order (no LDS x staging).
// grid = B*16; block = 256 tokens as 4 sub-tiles of 64. 4 waves.
__launch_bounds__(256, 3)
__global__ void kbig_fast(const ushort* __restrict__ xgs, const ushort* __restrict__ qg,
                          const ushort* __restrict__ wk, const ushort* __restrict__ wvw,
                          const float* __restrict__ qkb, float* __restrict__ denom,
                          float* __restrict__ partials) {
    int b = blockIdx.x >> 4, chunk = blockIdx.x & 15;
    int tid = threadIdx.x;
    int lane = tid & 63, w = tid >> 6;
    int l15 = lane & 15, quad = lane >> 4;

    __shared__ ushort kvs[18432];       // kt [n][e] pitch 264 (16896) OR vtT [d][n] pitch 72 (18432)
    __shared__ ushort attns[16 * 72];   // attn [s][n] pitch 72

    f32x4 pacc[4];
    #pragma unroll
    for (int u2 = 0; u2 < 4; u2++) pacc[u2] = f32x4{0.f, 0.f, 0.f, 0.f};
    float dsum = 0.f;
    float4 qo = *(const float4*)(qkb + b * 16 + quad * 4);

    #pragma unroll 1
    for (int sub = 0; sub < 4; sub++) {
        int tile0 = b * 256 + chunk * 16 + sub * 4;   // 4 token-tiles of 16

        // ===== K projection: kt[n][e] = sum_d x[n,d]*kW[e,d] (bias folded via qkb) =====
        f32x4 acc[4][4];
        #pragma unroll
        for (int t = 0; t < 4; t++)
            #pragma unroll
            for (int u = 0; u < 4; u++) acc[t][u] = f32x4{0.f, 0.f, 0.f, 0.f};
        #pragma unroll
        for (int ds = 0; ds < 8; ds++) {
            short8 a[4], bfr[4];
            #pragma unroll
            for (int t = 0; t < 4; t++)
                a[t] = *(const short8*)(xgs + (((size_t)(tile0 + t) * 8 + ds) * 64 + lane) * 8);
            #pragma unroll
            for (int u = 0; u < 4; u++)
                bfr[u] = *(const short8*)(wk + ((ds * 16 + (w * 4 + u)) * 64 + lane) * 8);
            #pragma unroll
            for (int t = 0; t < 4; t++)
                #pragma unroll
                for (int u = 0; u < 4; u++)
                    acc[t][u] = __builtin_amdgcn_mfma_f32_16x16x32_bf16(a[t], bfr[u], acc[t][u], 0, 0, 0);
        }
        // C/D layout: col = lane&15, row = quad*4+reg  -> kt[n][e] bf16
        #pragma unroll
        for (int t = 0; t < 4; t++)
            #pragma unroll
            for (int u = 0; u < 4; u++)
                #pragma unroll
                for (int r = 0; r < 4; r++)
                    kvs[(t * 16 + quad * 4 + r) * 264 + w * 64 + u * 16 + l15] = f2bf(acc[t][u][r]);
        __syncthreads();

        // ===== dist tile [16s x 16n] for n-tile w; q pre-scaled by 1/16 =====
        f32x4 dc = f32x4{0.f, 0.f, 0.f, 0.f};
        #pragma unroll
        for (int ds = 0; ds < 8; ds++) {
            short8 aq = *(const short8*)(qg + (b * 16 + l15) * 256 + ds * 32 + quad * 8);
            short8 bk = *(const short8*)(&kvs[(w * 16 + l15) * 264 + ds * 32 + quad * 8]);
            dc = __builtin_amdgcn_mfma_f32_16x16x32_bf16(aq, bk, dc, 0, 0, 0);
        }
        dc[0] += qo.x; dc[1] += qo.y; dc[2] += qo.z; dc[3] += qo.w;   // + q.kb per slot
        // softmax over 16 slots (4 regs x 4 quads; n = w*16+l15 fixed per lane)
        float mx = fmaxf(fmaxf(dc[0], dc[1]), fmaxf(dc[2], dc[3]));
        mx = fmaxf(mx, __shfl_xor(mx, 16));
        mx = fmaxf(mx, __shfl_xor(mx, 32));
        float e0 = __expf(dc[0] - mx), e1 = __expf(dc[1] - mx);
        float e2 = __expf(dc[2] - mx), e3 = __expf(dc[3] - mx);
        float lsum = e0 + e1 + e2 + e3;
        lsum += __shfl_xor(lsum, 16); lsum += __shfl_xor(lsum, 32);
        float inv = 1.f / lsum;
        attns[(quad * 4 + 0) * 72 + w * 16 + l15] = f2bf(e0 * inv);
        attns[(quad * 4 + 1) * 72 + w * 16 + l15] = f2bf(e1 * inv);
        attns[(quad * 4 + 2) * 72 + w * 16 + l15] = f2bf(e2 * inv);
        attns[(quad * 4 + 3) * 72 + w * 16 + l15] = f2bf(e3 * inv);
        __syncthreads();   // kt reads done; attn visible

        // ===== V projection -> vtT[d][n] pitch 72 =====
        #pragma unroll
        for (int t = 0; t < 4; t++)
            #pragma unroll
            for (int u = 0; u < 4; u++) acc[t][u] = f32x4{0.f, 0.f, 0.f, 0.f};
        #pragma unroll
        for (int ds = 0; ds < 8; ds++) {
            short8 a[4], bfr[4];
            #pragma unroll
            for (int t = 0; t < 4; t++)
                a[t] = *(const short8*)(xgs + (((size_t)(tile0 + t) * 8 + ds) * 64 + lane) * 8);
            #pragma unroll
            for (int u = 0; u < 4; u++)
                bfr[u] = *(const short8*)(wvw + ((ds * 16 + (w * 4 + u)) * 64 + lane) * 8);
            #pragma unroll
            for (int t = 0; t < 4; t++)
                #pragma unroll
                for (int u = 0; u < 4; u++)
                    acc[t][u] = __builtin_amdgcn_mfma_f32_16x16x32_bf16(a[t], bfr[u], acc[t][u], 0, 0, 0);
        }
        #pragma unroll
        for (int t = 0; t < 4; t++)
            #pragma unroll
            for (int u = 0; u < 4; u++) {
                ushort4 pk;
                pk.x = f2bf(acc[t][u][0]); pk.y = f2bf(acc[t][u][1]);
                pk.z = f2bf(acc[t][u][2]); pk.w = f2bf(acc[t][u][3]);
                *(ushort4*)(&kvs[(w * 64 + u * 16 + l15) * 72 + t * 16 + quad * 4]) = pk;
            }
        __syncthreads();

        // ===== denom partial (register accumulate) =====
        if (tid < 16) {
            float s = 0.f;
            for (int n = 0; n < 64; n++) s += bf2f(attns[tid * 72 + n]);
            dsum += s;
        }

        // ===== PV: pacc[s][d] += sum_n attn[s,n]*vt[n,d]; wave w owns d in [w*64,w*64+64) =====
        #pragma unroll
        for (int ns = 0; ns < 2; ns++) {
            short8 aa = *(const short8*)(&attns[l15 * 72 + ns * 32 + quad * 8]);
            #pragma unroll
            for (int u2 = 0; u2 < 4; u2++) {
                short8 bv8 = *(const short8*)(&kvs[(w * 64 + u2 * 16 + l15) * 72 + ns * 32 + quad * 8]);
                pacc[u2] = __builtin_amdgcn_mfma_f32_16x16x32_bf16(aa, bv8, pacc[u2], 0, 0, 0);
            }
        }
        __syncthreads();   // protect kvs/attns before next sub-tile
    }

    if (tid < 16) atomicAdd(&denom[b * 16 + tid], dsum);

    // partials[b][chunk][s][d]
    float* pout = partials + ((size_t)(b * 16 + chunk) * 16) * 256;
    #pragma unroll
    for (int u2 = 0; u2 < 4; u2++)
        #pragma unroll
        for (int r = 0; r < 4; r++)
            pout[(quad * 4 + r) * 256 + w * 64 + u2 * 16 + l15] = pacc[u2][r];
}

// ---------------- SLOW fallback (R2-proven): LN0 inline, LDS x staging ---------------
__launch_bounds__(256)
__global__ void kbig_slow(const float* __restrict__ inp, const float* __restrict__ ln0w,
                          const float* __restrict__ ln0b, const float* __restrict__ sums,
                          const ushort* __restrict__ qg,
                          const ushort* __restrict__ wk, const ushort* __restrict__ wvw,
                          const float* __restrict__ qkb, float* __restrict__ denom,
                          float* __restrict__ partials) {
    int b = blockIdx.x >> 4, chunk = blockIdx.x & 15;
    int tid = threadIdx.x;
    int lane = tid & 63, w = tid >> 6;
    int l15 = lane & 15, quad = lane >> 4;

    __shared__ ushort xtile[64 * 264];
    __shared__ ushort kvs[18432];
    __shared__ ushort attns[16 * 72];

    float mean = sums[b] * (1.f / 1048576.f);
    float rstd = rsqrtf(sums[64 + b] * (1.f / 1048576.f) - mean * mean + LN_EPS);

    f32x4 pacc[4];
    #pragma unroll
    for (int u2 = 0; u2 < 4; u2++) pacc[u2] = f32x4{0.f, 0.f, 0.f, 0.f};
    float dsum = 0.f;
    float4 qo = *(const float4*)(qkb + b * 16 + quad * 4);

    for (int sub = 0; sub < 4; sub++) {
        {
            const float4* xp = (const float4*)inp + ((size_t)b * 4096 + chunk * 256 + sub * 64) * 64;
            const float4* wp = (const float4*)ln0w + (chunk * 256 + sub * 64) * 64;
            const float4* bp = (const float4*)ln0b + (chunk * 256 + sub * 64) * 64;
            #pragma unroll
            for (int l = 0; l < 16; l++) {
                int i = l * 256 + tid;
                float4 v = xp[i], w4 = wp[i], b4 = bp[i];
                ushort4 o;
                o.x = f2bf((v.x - mean) * rstd * w4.x + b4.x);
                o.y = f2bf((v.y - mean) * rstd * w4.y + b4.y);
                o.z = f2bf((v.z - mean) * rstd * w4.z + b4.z);
                o.w = f2bf((v.w - mean) * rstd * w4.w + b4.w);
                *(ushort4*)(&xtile[(i >> 6) * 264 + (i & 63) * 4]) = o;
            }
        }
        __syncthreads();

        f32x4 acc[4][4];
        #pragma unroll
        for (int t = 0; t < 4; t++)
            #pragma unroll
            for (int u = 0; u < 4; u++) acc[t][u] = f32x4{0.f, 0.f, 0.f, 0.f};
        #pragma unroll
        for (int ds = 0; ds < 8; ds++) {
            short8 a[4], bfr[4];
            #pragma unroll
            for (int t = 0; t < 4; t++)
                a[t] = *(const short8*)(&xtile[(t * 16 + l15) * 264 + ds * 32 + quad * 8]);
            #pragma unroll
            for (int u = 0; u < 4; u++)
                bfr[u] = *(const short8*)(wk + ((ds * 16 + (w * 4 + u)) * 64 + lane) * 8);
            #pragma unroll
            for (int t = 0; t < 4; t++)
                #pragma unroll
                for (int u = 0; u < 4; u++)
                    acc[t][u] = __builtin_amdgcn_mfma_f32_16x16x32_bf16(a[t], bfr[u], acc[t][u], 0, 0, 0);
        }
        #pragma unroll
        for (int t = 0; t < 4; t++)
            #pragma unroll
            for (int u = 0; u < 4; u++)
                #pragma unroll
                for (int r = 0; r < 4; r++)
                    kvs[(t * 16 + quad * 4 + r) * 264 + w * 64 + u * 16 + l15] = f2bf(acc[t][u][r]);
        __syncthreads();

        f32x4 dc = f32x4{0.f, 0.f, 0.f, 0.f};
        #pragma unroll
        for (int ds = 0; ds < 8; ds++) {
            short8 aq = *(const short8*)(qg + (b * 16 + l15) * 256 + ds * 32 + quad * 8);
            short8 bk = *(const short8*)(&kvs[(w * 16 + l15) * 264 + ds * 32 + quad * 8]);
            dc = __builtin_amdgcn_mfma_f32_16x16x32_bf16(aq, bk, dc, 0, 0, 0);
        }
        dc[0] += qo.x; dc[1] += qo.y; dc[2] += qo.z; dc[3] += qo.w;
        float mx = fmaxf(fmaxf(dc[0], dc[1]), fmaxf(dc[2], dc[3]));
        mx = fmaxf(mx, __shfl_xor(mx, 16));
        mx = fmaxf(mx, __shfl_xor(mx, 32));
        float e0 = __expf(dc[0] - mx), e1 = __expf(dc[1] - mx);
        float e2 = __expf(dc[2] - mx), e3 = __expf(dc[3] - mx);
        float lsum = e0 + e1 + e2 + e3;
        lsum += __shfl_xor(lsum, 16); lsum += __shfl_xor(lsum, 32);
        float inv = 1.f / lsum;
        attns[(quad * 4 + 0) * 72 + w * 16 + l15] = f2bf(e0 * inv);
        attns[(quad * 4 + 1) * 72 + w * 16 + l15] = f2bf(e1 * inv);
        attns[(quad * 4 + 2) * 72 + w * 16 + l15] = f2bf(e2 * inv);
        attns[(quad * 4 + 3) * 72 + w * 16 + l15] = f2bf(e3 * inv);
        __syncthreads();

        #pragma unroll
        for (int t = 0; t < 4; t++)
            #pragma unroll
            for (int u = 0; u < 4; u++) acc[t][u] = f32x4{0.f, 0.f, 0.f, 0.f};
        #pragma unroll
        for (int ds = 0; ds < 8; ds++) {
            short8 a[4], bfr[4];
            #pragma unroll
            for (int t = 0; t < 4; t++)
                a[t] = *(const short8*)(&xtile[(t * 16 + l15) * 264 + ds * 32 + quad * 8]);
            #pragma unroll
            for (int u = 0; u < 4; u++)
                bfr[u] = *(const short8*)(wvw + ((ds * 16 + (w * 4 + u)) * 64 + lane) * 8);
            #pragma unroll
            for (int t = 0; t < 4; t++)
                #pragma unroll
                for (int u = 0; u < 4; u++)
                    acc[t][u] = __builtin_amdgcn_mfma_f32_16x16x32_bf16(a[t], bfr[u], acc[t][u], 0, 0, 0);
        }
        #pragma unroll
        for (int t = 0; t < 4; t++)
            #pragma unroll
            for (int u = 0; u < 4; u++) {
                ushort4 pk;
                pk.x = f2bf(acc[t][u][0]); pk.y = f2bf(acc[t][u][1]);
                pk.z = f2bf(acc[t][u][2]); pk.w = f2bf(acc[t][u][3]);
                *(ushort4*)(&kvs[(w * 64 + u * 16 + l15) * 72 + t * 16 + quad * 4]) = pk;
            }
        __syncthreads();

        if (tid < 16) {
            float s = 0.f;
            for (int n = 0; n < 64; n++) s += bf2f(attns[tid * 72 + n]);
            dsum += s;
        }

        #pragma unroll
        for (int ns = 0; ns < 2; ns++) {
            short8 aa = *(const short8*)(&attns[l15 * 72 + ns * 32 + quad * 8]);
            #pragma unroll
            for (int u2 = 0; u2 < 4; u2++) {
                short8 bv8 = *(const short8*)(&kvs[(w * 64 + u2 * 16 + l15) * 72 + ns * 32 + quad * 8]);
                pacc[u2] = __builtin_amdgcn_mfma_f32_16x16x32_bf16(aa, bv8, pacc[u2], 0, 0, 0);
            }
        }
        __syncthreads();
    }

    if (tid < 16) atomicAdd(&denom[b * 16 + tid], dsum);

    float* pout = partials + ((size_t)(b * 16 + chunk) * 16) * 256;
    #pragma unroll
    for (int u2 = 0; u2 < 4; u2++)
        #pragma unroll
        for (int r = 0; r < 4; r++)
            pout[(quad * 4 + r) * 256 + w * 64 + u2 * 16 + l15] = pacc[u2][r];
}

// ---------------- reduce partials over 16 chunks; apply v-bias + denom division -----
__global__ void kred(const float* __restrict__ partials, const float* __restrict__ denom,
                     const float* __restrict__ vb, float* __restrict__ slots) {
    int b = blockIdx.x >> 4, s = blockIdx.x & 15, t = threadIdx.x;
    float A = denom[b * 16 + s];
    const float* p = partials + (size_t)b * 65536 + s * 256 + t;
    float sum = 0.f;
    #pragma unroll
    for (int c = 0; c < 16; c++) sum += p[c * 4096];
    slots[b * 4096 + s * 256 + t] = (sum + vb[t] * A) / (A + 1e-7f);
}

// ---------------- LN2 + MLP + residual ----------------------------------------------
__global__ void kfin(const float* __restrict__ slots_in, const float* __restrict__ ln2w,
                     const float* __restrict__ ln2b, const float* __restrict__ m1WT,
                     const float* __restrict__ m1b, const float* __restrict__ m2WT,
                     const float* __restrict__ m2b, float* __restrict__ slots_out,
                     float* __restrict__ final_out, int write_final) {
    int b = blockIdx.x, t = threadIdx.x;
    __shared__ float raws[4096];
    __shared__ float s2[4096];
    __shared__ float h[16 * 512];
    __shared__ float r1[256], r2[256];
    const float* sp = slots_in + b * 4096;
    float s = 0.f, sq = 0.f;
    #pragma unroll
    for (int k = 0; k < 16; k++) {
        float v = sp[k * 256 + t]; raws[k * 256 + t] = v; s += v; sq += v * v;
    }
    r1[t] = s; r2[t] = sq; __syncthreads();
    for (int st = 128; st > 0; st >>= 1) {
        if (t < st) { r1[t] += r1[t + st]; r2[t] += r2[t + st]; }
        __syncthreads();
    }
    float m  = r1[0] * (1.f / 4096.f);
    float rs = rsqrtf(r2[0] * (1.f / 4096.f) - m * m + LN_EPS);
    #pragma unroll
    for (int k = 0; k < 16; k++) {
        int i = k * 256 + t;
        s2[i] = (raws[i] - m) * rs * ln2w[i] + ln2b[i];
    }
    __syncthreads();
    #pragma unroll
    for (int jj = 0; jj < 2; jj++) {
        int j = t + jj * 256;
        float a[16];
        #pragma unroll
        for (int k = 0; k < 16; k++) a[k] = 0.f;
        for (int d = 0; d < 256; d++) {
            float wvv = m1WT[d * 512 + j];
            #pragma unroll
            for (int k = 0; k < 16; k++) a[k] += s2[k * 256 + d] * wvv;
        }
        float bias = m1b[j];
        #pragma unroll
        for (int k = 0; k < 16; k++) h[k * 512 + j] = fmaxf(a[k] + bias, 0.f);
    }
    __syncthreads();
    float a2[16];
    #pragma unroll
    for (int k = 0; k < 16; k++) a2[k] = 0.f;
    for (int j = 0; j < 512; j++) {
        float wvv = m2WT[j * 256 + t];
        #pragma unroll
        for (int k = 0; k < 16; k++) a2[k] += h[k * 512 + j] * wvv;
    }
    float bias2 = m2b[t];
    #pragma unroll
    for (int k = 0; k < 16; k++) {
        float val = raws[k * 256 + t] + a2[k] + bias2;
        slots_out[b * 4096 + k * 256 + t] = val;
        if (write_final) final_out[b * 4096 + k * 256 + t] = val;
    }
}

extern "C" void kernel_launch(void* const* d_in, const int* in_sizes, int n_in,
                              void* d_out, int out_size, void* d_ws, size_t ws_size,
                              hipStream_t stream) {
    const float* inputs     = (const float*)d_in[0];
    const float* slots_init = (const float*)d_in[1];
    const float* mu         = (const float*)d_in[2];
    const float* logsig     = (const float*)d_in[3];
    const float* ln0w       = (const float*)d_in[4];
    const float* ln0b       = (const float*)d_in[5];
    const float* ln1w       = (const float*)d_in[6];
    const float* ln1b       = (const float*)d_in[7];
    const float* ln2w       = (const float*)d_in[8];
    const float* ln2b       = (const float*)d_in[9];
    const float* qW         = (const float*)d_in[10];
    const float* qb         = (const float*)d_in[11];
    const float* kW         = (const float*)d_in[12];
    const float* kb         = (const float*)d_in[13];
    const float* vW         = (const float*)d_in[14];
    const float* vb         = (const float*)d_in[15];
    const float* m1W        = (const float*)d_in[16];
    const float* m1b        = (const float*)d_in[17];
    const float* m2W        = (const float*)d_in[18];
    const float* m2b        = (const float*)d_in[19];

    const size_t XGS_BYTES = 134217728;   // 64*4096*256 bf16
    size_t small_need = 16777216 + 524288 + 1048576 + 786432 + 1572864 + 1572864
                      + 393216 + 393216 + 4096 + 4096 + 512;
    int big = (ws_size >= XGS_BYTES + small_need) ? 1 : 0;

    char* ws = (char*)d_ws;
    ushort* xgs = (ushort*)ws;                         // fast path only, 128 MB
    char* base = ws + (big ? XGS_BYTES : 0);
    float*  partials= (float*)(base);                  // 16,777,216 B
    ushort* qg      = (ushort*)(base + 16777216);      //    524,288 B
    float*  slots   = (float*)(base + 17301504);       //  1,048,576 B
    float*  qWT     = (float*)(base + 18350080);       //    786,432 B
    float*  m1WT    = (float*)(base + 19136512);       //  1,572,864 B
    float*  m2WT    = (float*)(base + 20709376);       //  1,572,864 B
    ushort* kwsw    = (ushort*)(base + 22282240);      //    393,216 B
    ushort* vwsw    = (ushort*)(base + 22675456);      //    393,216 B
    float*  denom   = (float*)(base + 23068672);       //      4,096 B
    float*  qkb     = (float*)(base + 23072768);       //      4,096 B
    float*  sums    = (float*)(base + 23076864);       //        512 B

    kinit<<<1024, 256, 0, stream>>>(slots_init, mu, logsig, slots, sums);
    kprep2<<<1536, 256, 0, stream>>>(kW, vW, kwsw, vwsw);
    ktrans<<<240, 256, 0, stream>>>(qW, m1W, m2W, qWT, m1WT, m2WT);
    l0a<<<2048, 256, 0, stream>>>(inputs, sums);
    if (big) l0bs<<<32768, 256, 0, stream>>>(inputs, ln0w, ln0b, sums, xgs);

    for (int it = 0; it < 3; it++) {
        kq<<<64, 256, 0, stream>>>(slots, ln1w, ln1b, qWT + it * 65536, qb + it * 256,
                                   kb + it * 256, qg, qkb, denom);
        if (big) {
            kbig_fast<<<1024, 256, 0, stream>>>(xgs, qg, kwsw + it * 65536, vwsw + it * 65536,
                                                qkb, denom, partials);
        } else {
            kbig_slow<<<1024, 256, 0, stream>>>(inputs, ln0w, ln0b, sums, qg,
                                                kwsw + it * 65536, vwsw + it * 65536,
                                                qkb, denom, partials);
        }
        kred<<<1024, 256, 0, stream>>>(partials, denom, vb + it * 256, slots);
        kfin<<<64, 256, 0, stream>>>(slots, ln2w, ln2b, m1WT + it * 131072, m1b + it * 512,
                                     m2WT + it * 131072, m2b + it * 256, slots,
                                     (float*)d_out, it == 2 ? 1 : 0);
    }
}

// Round 4
// 1088.005 us; speedup vs baseline: 2.2857x; 2.2857x over previous
//
#include <hip/hip_runtime.h>
#include <hip/hip_bf16.h>

#define LN_EPS 1e-5f

typedef __attribute__((ext_vector_type(8))) short short8;   // 8 bf16
typedef __attribute__((ext_vector_type(4))) float f32x4;    // MFMA C/D frag

__device__ __forceinline__ ushort f2bf(float f) {
    __hip_bfloat16 h = __float2bfloat16(f);
    return *reinterpret_cast<ushort*>(&h);
}
__device__ __forceinline__ float bf2f(ushort u) {
    union { float f; unsigned int i; } c; c.i = ((unsigned int)u) << 16; return c.f;
}

// ---------------- init: slots0 = mu + exp(logsigma)*slots_init; zero LN0 sums --------
__global__ void kinit(const float* __restrict__ slots_init, const float* __restrict__ mu,
                      const float* __restrict__ logsig, float* __restrict__ slots,
                      float* __restrict__ sums) {
    int i = blockIdx.x * 256 + threadIdx.x;    // 262144 exactly
    int d = i & 255;
    slots[i] = mu[d] + __expf(logsig[d]) * slots_init[i];
    if (blockIdx.x == 0 && threadIdx.x < 128) sums[threadIdx.x] = 0.f;
}

// ---------------- tiled 64x64 transposes -> bf16: qWT, m1WT, m2WT, vWT ---------------
// qWT[d][e]=qW[e][d]; m1WT[d][j]=m1W[j][d]; m2WT[j][d]=m2W[d][j]; vWT[e][d]=vW[d][e]
__global__ void ktrans(const float* __restrict__ qW, const float* __restrict__ m1W,
                       const float* __restrict__ m2W, const float* __restrict__ vW,
                       ushort* __restrict__ qWT, ushort* __restrict__ m1WT,
                       ushort* __restrict__ m2WT, ushort* __restrict__ vWT) {
    __shared__ float tile[64][65];
    int blk = blockIdx.x, t = threadIdx.x;
    const float* src; ushort* dst; int R, C, tr, tc;
    if (blk < 48) {
        int it = blk >> 4, rem = blk & 15;
        R = 256; C = 256; tr = rem >> 2; tc = rem & 3;
        src = qW + it * 65536; dst = qWT + it * 65536;
    } else if (blk < 144) {
        int li = blk - 48; int it = li >> 5, rem = li & 31;
        R = 512; C = 256; tr = rem >> 2; tc = rem & 3;
        src = m1W + it * 131072; dst = m1WT + it * 131072;
    } else if (blk < 240) {
        int li = blk - 144; int it = li >> 5, rem = li & 31;
        R = 256; C = 512; tr = rem >> 3; tc = rem & 7;
        src = m2W + it * 131072; dst = m2WT + it * 131072;
    } else {
        int li = blk - 240; int it = li >> 4, rem = li & 15;
        R = 256; C = 256; tr = rem >> 2; tc = rem & 3;
        src = vW + it * 65536; dst = vWT + it * 65536;
    }
    int col = t & 63, rq = t >> 6;
    #pragma unroll
    for (int r = 0; r < 16; r++) {
        int row = r * 4 + rq;
        tile[row][col] = src[(tr * 64 + row) * C + tc * 64 + col];
    }
    __syncthreads();
    #pragma unroll
    for (int r = 0; r < 16; r++) {
        int row = r * 4 + rq;
        dst[(tc * 64 + row) * R + tr * 64 + col] = f2bf(tile[col][row]);
    }
}

// ---------------- LN0 pass 1: per-batch sum/sumsq over N*DIN = 1M elems -------------
__global__ void l0a(const float* __restrict__ inp, float* __restrict__ sums) {
    int b = blockIdx.x >> 5, seg = blockIdx.x & 31;
    const float4* p = (const float4*)inp + (size_t)b * 262144 + seg * 8192 + threadIdx.x;
    float s = 0.f, sq = 0.f;
    #pragma unroll
    for (int k = 0; k < 32; k++) {
        float4 v = p[k * 256];
        s  += v.x + v.y + v.z + v.w;
        sq += v.x * v.x + v.y * v.y + v.z * v.z + v.w * v.w;
    }
    __shared__ float r1[256], r2[256];
    r1[threadIdx.x] = s; r2[threadIdx.x] = sq; __syncthreads();
    for (int st = 128; st > 0; st >>= 1) {
        if (threadIdx.x < st) { r1[threadIdx.x] += r1[threadIdx.x + st]; r2[threadIdx.x] += r2[threadIdx.x + st]; }
        __syncthreads();
    }
    if (threadIdx.x == 0) { atomicAdd(&sums[b], r1[0]); atomicAdd(&sums[64 + b], r2[0]); }
}

// ---------------- LN0 pass 2: normalize + write bf16 x in MFMA-frag order ------------
// xgs[tile16(16384)][ds(8)][lane(64)][j(8)]: x[tile16*16+(lane&15)][ds*32+(lane>>4)*8+j]
__global__ void l0bs(const float* __restrict__ inp, const float* __restrict__ ln0w,
                     const float* __restrict__ ln0b, const float* __restrict__ sums,
                     ushort* __restrict__ xgs) {
    int tid = threadIdx.x;
    int gw = blockIdx.x * 4 + (tid >> 6);      // 131072 wave tasks
    int lane = tid & 63, l15 = lane & 15, quad = lane >> 4;
    int tile16 = gw >> 3, ds = gw & 7;
    int token = tile16 * 16 + l15;             // global token (b*4096 + n)
    int b = tile16 >> 8;
    int n = token & 4095;
    int dcol = ds * 32 + quad * 8;
    float mean = sums[b] * (1.f / 1048576.f);
    float rstd = rsqrtf(sums[64 + b] * (1.f / 1048576.f) - mean * mean + LN_EPS);
    const float4* xp = (const float4*)(inp + (size_t)token * 256 + dcol);
    const float4* wp = (const float4*)(ln0w + n * 256 + dcol);
    const float4* bp = (const float4*)(ln0b + n * 256 + dcol);
    float4 v0 = xp[0], v1 = xp[1];
    float4 w0 = wp[0], w1 = wp[1];
    float4 b0 = bp[0], b1 = bp[1];
    ushort o[8];
    o[0] = f2bf((v0.x - mean) * rstd * w0.x + b0.x);
    o[1] = f2bf((v0.y - mean) * rstd * w0.y + b0.y);
    o[2] = f2bf((v0.z - mean) * rstd * w0.z + b0.z);
    o[3] = f2bf((v0.w - mean) * rstd * w0.w + b0.w);
    o[4] = f2bf((v1.x - mean) * rstd * w1.x + b1.x);
    o[5] = f2bf((v1.y - mean) * rstd * w1.y + b1.y);
    o[6] = f2bf((v1.z - mean) * rstd * w1.z + b1.z);
    o[7] = f2bf((v1.w - mean) * rstd * w1.w + b1.w);
    *(short8*)(xgs + ((size_t)gw * 64 + lane) * 8) = *(short8*)o;
}

// ---------------- per-iter: LN1(slots) -> q' = (q+qb)/16 -> qk = q'@kW (bf16 frags) --
// Also qkb[s] = q'.kb, denom = 0.  grid 64 (one block per batch).
__global__ void kq(const float* __restrict__ slots, const float* __restrict__ ln1w,
                   const float* __restrict__ ln1b, const ushort* __restrict__ qWT,
                   const float* __restrict__ qb, const float* __restrict__ kW,
                   const float* __restrict__ kb,
                   ushort* __restrict__ qkf, float* __restrict__ qkb,
                   float* __restrict__ denom) {
    int b = blockIdx.x, t = threadIdx.x;
    __shared__ float sl[4096];
    __shared__ float qs[4096];
    __shared__ float r1[256], r2[256];
    const float* sp = slots + b * 4096;
    float vals[16]; float s = 0.f, sq = 0.f;
    #pragma unroll
    for (int k = 0; k < 16; k++) { float v = sp[k * 256 + t]; vals[k] = v; s += v; sq += v * v; }
    r1[t] = s; r2[t] = sq; __syncthreads();
    for (int st = 128; st > 0; st >>= 1) {
        if (t < st) { r1[t] += r1[t + st]; r2[t] += r2[t + st]; }
        __syncthreads();
    }
    float m  = r1[0] * (1.f / 4096.f);
    float rs = rsqrtf(r2[0] * (1.f / 4096.f) - m * m + LN_EPS);
    #pragma unroll
    for (int k = 0; k < 16; k++)
        sl[k * 256 + t] = (vals[k] - m) * rs * ln1w[k * 256 + t] + ln1b[k * 256 + t];
    __syncthreads();
    // q'[s, e=t] = (sum_d sl[s,d]*qW[e,d] + qb[e]) / 16
    {
        float acc[16];
        #pragma unroll
        for (int k = 0; k < 16; k++) acc[k] = 0.f;
        for (int d = 0; d < 256; d++) {
            float wv = bf2f(qWT[d * 256 + t]);
            #pragma unroll
            for (int k = 0; k < 16; k++) acc[k] += sl[k * 256 + d] * wv;
        }
        float qbv = qb[t];
        #pragma unroll
        for (int k = 0; k < 16; k++) qs[k * 256 + t] = (acc[k] + qbv) * (1.f / 16.f);
    }
    __syncthreads();
    // qk[s, d=t] = sum_e q'[s,e]*kW[e,d]  -> bf16 A-frag layout
    {
        float acc[16];
        #pragma unroll
        for (int k = 0; k < 16; k++) acc[k] = 0.f;
        for (int e = 0; e < 256; e++) {
            float wv = kW[e * 256 + t];
            #pragma unroll
            for (int k = 0; k < 16; k++) acc[k] += qs[k * 256 + e] * wv;
        }
        int d = t;
        int ds = d >> 5, quad = (d >> 3) & 3, j = d & 7;
        #pragma unroll
        for (int k = 0; k < 16; k++)
            qkf[(size_t)(b * 8 + ds) * 512 + (k + 16 * quad) * 8 + j] = f2bf(acc[k]);
    }
    if (t < 16) {
        float kbs = 0.f;
        for (int e = 0; e < 256; e++) kbs += qs[t * 256 + e] * kb[e];
        qkb[b * 16 + t] = kbs;
    } else if (t < 32) {
        denom[b * 16 + (t - 16)] = 0.f;
    }
}

// ---------------- THE hot kernel: dist = qk@x^T (+qkb) -> softmax -> ax = attn@x -----
// grid = B*16; block = 256 tokens as 4 sub-tiles of 64; 4 waves; xgs streamed once.
__launch_bounds__(256, 4)
__global__ void katt(const ushort* __restrict__ xgs, const ushort* __restrict__ qkf,
                     const float* __restrict__ qkb, float* __restrict__ denom,
                     float* __restrict__ partials) {
    int b = blockIdx.x >> 4, chunk = blockIdx.x & 15;
    int tid = threadIdx.x;
    int lane = tid & 63, w = tid >> 6;
    int l15 = lane & 15, quad = lane >> 4;

    __shared__ ushort xt[64 * 268];     // sub-tile x [n_local][d], pitch 268 (34.3 KB)
    __shared__ ushort attn[16 * 72];    // attn [s][n_local], pitch 72

    // qk A-frags: invariant across the whole block (one batch)
    short8 qkfr[8];
    #pragma unroll
    for (int ds = 0; ds < 8; ds++)
        qkfr[ds] = *(const short8*)(qkf + ((size_t)(b * 8 + ds) * 512 + lane * 8));
    float4 qo = *(const float4*)(qkb + b * 16 + quad * 4);

    f32x4 pacc[4];
    #pragma unroll
    for (int u = 0; u < 4; u++) pacc[u] = f32x4{0.f, 0.f, 0.f, 0.f};
    float dsum = 0.f;

    int tile0 = b * 256 + chunk * 16;   // global 16-token tile base

    // prefetch sub 0 into regs (each wave stages 8 KB = 8 frag-lines)
    short8 pf[8];
    #pragma unroll
    for (int i = 0; i < 8; i++) {
        int task = w * 8 + i;           // tt = task>>3 (0..3), ds = task&7
        pf[i] = *(const short8*)(xgs + (((size_t)(tile0 + (task >> 3)) * 8 + (task & 7)) * 64 + lane) * 8);
    }

    #pragma unroll 1
    for (int sub = 0; sub < 4; sub++) {
        __syncthreads();                // prior ax done reading xt
        #pragma unroll
        for (int i = 0; i < 8; i++) {
            int task = w * 8 + i; int tt = task >> 3, ds = task & 7;
            *(short8*)(&xt[(tt * 16 + l15) * 268 + ds * 32 + quad * 8]) = pf[i];
        }
        __syncthreads();
        if (sub < 3) {                  // prefetch next sub while computing
            #pragma unroll
            for (int i = 0; i < 8; i++) {
                int task = w * 8 + i;
                pf[i] = *(const short8*)(xgs + (((size_t)(tile0 + (sub + 1) * 4 + (task >> 3)) * 8 + (task & 7)) * 64 + lane) * 8);
            }
        }
        // ===== dist tile [16s x 16n], wave w owns n_local [w*16, w*16+16) =====
        f32x4 dc = f32x4{0.f, 0.f, 0.f, 0.f};
        #pragma unroll
        for (int ds = 0; ds < 8; ds++) {
            short8 bk = *(const short8*)(&xt[(w * 16 + l15) * 268 + ds * 32 + quad * 8]);
            dc = __builtin_amdgcn_mfma_f32_16x16x32_bf16(qkfr[ds], bk, dc, 0, 0, 0);
        }
        dc[0] += qo.x; dc[1] += qo.y; dc[2] += qo.z; dc[3] += qo.w;
        // softmax over the 16 slots (4 regs x 4 quads; n fixed per lane)
        float mx = fmaxf(fmaxf(dc[0], dc[1]), fmaxf(dc[2], dc[3]));
        mx = fmaxf(mx, __shfl_xor(mx, 16));
        mx = fmaxf(mx, __shfl_xor(mx, 32));
        float e0 = __expf(dc[0] - mx), e1 = __expf(dc[1] - mx);
        float e2 = __expf(dc[2] - mx), e3 = __expf(dc[3] - mx);
        float lsum = e0 + e1 + e2 + e3;
        lsum += __shfl_xor(lsum, 16); lsum += __shfl_xor(lsum, 32);
        float inv = 1.f / lsum;
        attn[(quad * 4 + 0) * 72 + w * 16 + l15] = f2bf(e0 * inv);
        attn[(quad * 4 + 1) * 72 + w * 16 + l15] = f2bf(e1 * inv);
        attn[(quad * 4 + 2) * 72 + w * 16 + l15] = f2bf(e2 * inv);
        attn[(quad * 4 + 3) * 72 + w * 16 + l15] = f2bf(e3 * inv);
        __syncthreads();                // attn visible to all waves

        // denom partial
        if (tid < 16) {
            float ss = 0.f;
            for (int n = 0; n < 64; n++) ss += bf2f(attn[tid * 72 + n]);
            dsum += ss;
        }
        // ===== ax: pacc[s][d] += sum_n attn[s,n]*x[n,d]; wave w owns d [w*64,(w+1)*64) =====
        #pragma unroll
        for (int ns = 0; ns < 2; ns++) {
            short8 aa = *(const short8*)(&attn[l15 * 72 + ns * 32 + quad * 8]);
            #pragma unroll
            for (int u = 0; u < 4; u++) {
                ushort tmp[8];
                #pragma unroll
                for (int j = 0; j < 8; j++)
                    tmp[j] = xt[(ns * 32 + quad * 8 + j) * 268 + (w * 4 + u) * 16 + l15];
                pacc[u] = __builtin_amdgcn_mfma_f32_16x16x32_bf16(aa, *(short8*)tmp, pacc[u], 0, 0, 0);
            }
        }
    }

    if (tid < 16) atomicAdd(&denom[b * 16 + tid], dsum);

    float* pout = partials + (size_t)(b * 16 + chunk) * 4096;   // [s][d]
    #pragma unroll
    for (int u = 0; u < 4; u++)
        #pragma unroll
        for (int r = 0; r < 4; r++)
            pout[(quad * 4 + r) * 256 + (w * 4 + u) * 16 + l15] = pacc[u][r];
}

// ---------------- reduce chunks + apply vW^T + vb, divide by denom -------------------
// grid 256 = (b, d-quarter)
__global__ void kred2(const float* __restrict__ partials, const float* __restrict__ denom,
                      const ushort* __restrict__ vWT, const float* __restrict__ vb,
                      float* __restrict__ slots) {
    int b = blockIdx.x >> 2, dq = blockIdx.x & 3, t = threadIdx.x;
    __shared__ float axs[4096];
    __shared__ float dn[16];
    #pragma unroll
    for (int i = 0; i < 16; i++) {
        int idx = i * 256 + t;
        float ssum = 0.f;
        #pragma unroll
        for (int c = 0; c < 16; c++) ssum += partials[(size_t)b * 65536 + c * 4096 + idx];
        axs[idx] = ssum;
    }
    if (t < 16) dn[t] = denom[b * 16 + t];
    __syncthreads();
    int d = dq * 64 + (t & 63), sg = t >> 6;
    float acc[4];
    #pragma unroll
    for (int i = 0; i < 4; i++) acc[i] = 0.f;
    for (int e = 0; e < 256; e++) {
        float wv = bf2f(vWT[e * 256 + d]);
        #pragma unroll
        for (int i = 0; i < 4; i++) acc[i] += axs[(sg + i * 4) * 256 + e] * wv;
    }
    float vbd = vb[d];
    #pragma unroll
    for (int i = 0; i < 4; i++) {
        int s = sg + i * 4;
        float A = dn[s];
        slots[b * 4096 + s * 256 + d] = (acc[i] + vbd * A) / (A + 1e-7f);
    }
}

// ---------------- LN2 + MLP layer 1 (relu) -> htmp bf16; grid 256 = (b, h-quarter) ---
__global__ void kfin1(const float* __restrict__ slots_in, const float* __restrict__ ln2w,
                      const float* __restrict__ ln2b, const ushort* __restrict__ m1WT,
                      const float* __restrict__ m1b, ushort* __restrict__ htmp) {
    int b = blockIdx.x >> 2, hq = blockIdx.x & 3, t = threadIdx.x;
    __shared__ float s2[4096];
    __shared__ float r1[256], r2[256];
    const float* sp = slots_in + b * 4096;
    float vals[16]; float s = 0.f, sq = 0.f;
    #pragma unroll
    for (int k = 0; k < 16; k++) { float v = sp[k * 256 + t]; vals[k] = v; s += v; sq += v * v; }
    r1[t] = s; r2[t] = sq; __syncthreads();
    for (int st = 128; st > 0; st >>= 1) {
        if (t < st) { r1[t] += r1[t + st]; r2[t] += r2[t + st]; }
        __syncthreads();
    }
    float m  = r1[0] * (1.f / 4096.f);
    float rs = rsqrtf(r2[0] * (1.f / 4096.f) - m * m + LN_EPS);
    #pragma unroll
    for (int k = 0; k < 16; k++)
        s2[k * 256 + t] = (vals[k] - m) * rs * ln2w[k * 256 + t] + ln2b[k * 256 + t];
    __syncthreads();
    int j = hq * 128 + (t & 127), sg2 = t >> 7;   // s in {sg2, sg2+2, ..., sg2+14}
    float acc[8];
    #pragma unroll
    for (int i = 0; i < 8; i++) acc[i] = 0.f;
    for (int d = 0; d < 256; d++) {
        float wv = bf2f(m1WT[d * 512 + j]);
        #pragma unroll
        for (int i = 0; i < 8; i++) acc[i] += s2[(sg2 + i * 2) * 256 + d] * wv;
    }
    float bias = m1b[j];
    #pragma unroll
    for (int i = 0; i < 8; i++)
        htmp[b * 8192 + (sg2 + i * 2) * 512 + j] = f2bf(fmaxf(acc[i] + bias, 0.f));
}

// ---------------- MLP layer 2 + residual; grid 256 = (b, d-quarter) ------------------
__global__ void kfin2(const ushort* __restrict__ htmp, const ushort* __restrict__ m2WT,
                      const float* __restrict__ m2b, float* __restrict__ slots,
                      float* __restrict__ final_out, int write_final) {
    int b = blockIdx.x >> 2, dq = blockIdx.x & 3, t = threadIdx.x;
    __shared__ float hl[8192];
    #pragma unroll
    for (int i = 0; i < 32; i++) {
        int idx = i * 256 + t;
        hl[idx] = bf2f(htmp[b * 8192 + idx]);
    }
    __syncthreads();
    int d = dq * 64 + (t & 63), sg = t >> 6;
    float acc[4];
    #pragma unroll
    for (int i = 0; i < 4; i++) acc[i] = 0.f;
    for (int j = 0; j < 512; j++) {
        float wv = bf2f(m2WT[j * 256 + d]);
        #pragma unroll
        for (int i = 0; i < 4; i++) acc[i] += hl[(sg + i * 4) * 512 + j] * wv;
    }
    float bias2 = m2b[d];
    #pragma unroll
    for (int i = 0; i < 4; i++) {
        int s = sg + i * 4;
        float raw = slots[b * 4096 + s * 256 + d];
        float val = raw + acc[i] + bias2;
        slots[b * 4096 + s * 256 + d] = val;
        if (write_final) final_out[b * 4096 + s * 256 + d] = val;
    }
}

extern "C" void kernel_launch(void* const* d_in, const int* in_sizes, int n_in,
                              void* d_out, int out_size, void* d_ws, size_t ws_size,
                              hipStream_t stream) {
    const float* inputs     = (const float*)d_in[0];
    const float* slots_init = (const float*)d_in[1];
    const float* mu         = (const float*)d_in[2];
    const float* logsig     = (const float*)d_in[3];
    const float* ln0w       = (const float*)d_in[4];
    const float* ln0b       = (const float*)d_in[5];
    const float* ln1w       = (const float*)d_in[6];
    const float* ln1b       = (const float*)d_in[7];
    const float* ln2w       = (const float*)d_in[8];
    const float* ln2b       = (const float*)d_in[9];
    const float* qW         = (const float*)d_in[10];
    const float* qb         = (const float*)d_in[11];
    const float* kW         = (const float*)d_in[12];
    const float* kb         = (const float*)d_in[13];
    const float* vW         = (const float*)d_in[14];
    const float* vb         = (const float*)d_in[15];
    const float* m1W        = (const float*)d_in[16];
    const float* m1b        = (const float*)d_in[17];
    const float* m2W        = (const float*)d_in[18];
    const float* m2b        = (const float*)d_in[19];

    char* ws = (char*)d_ws;
    ushort* xgs     = (ushort*)(ws);                   // 134,217,728 B
    float*  partials= (float*)(ws + 134217728);        //  16,777,216 B
    ushort* qkf     = (ushort*)(ws + 150994944);       //     524,288 B
    ushort* htmp    = (ushort*)(ws + 151519232);       //   1,048,576 B
    float*  slots   = (float*)(ws + 152567808);        //   1,048,576 B
    ushort* qWT     = (ushort*)(ws + 153616384);       //     393,216 B
    ushort* m1WT    = (ushort*)(ws + 154009600);       //     786,432 B
    ushort* m2WT    = (ushort*)(ws + 154796032);       //     786,432 B
    ushort* vWT     = (ushort*)(ws + 155582464);       //     393,216 B
    float*  denom   = (float*)(ws + 155975680);        //       4,096 B
    float*  qkb     = (float*)(ws + 155979776);        //       4,096 B
    float*  sums    = (float*)(ws + 155983872);        //         512 B
    // total 155,984,384 B <= 157,295,104 B proven available in R3

    kinit<<<1024, 256, 0, stream>>>(slots_init, mu, logsig, slots, sums);
    ktrans<<<288, 256, 0, stream>>>(qW, m1W, m2W, vW, qWT, m1WT, m2WT, vWT);
    l0a<<<2048, 256, 0, stream>>>(inputs, sums);
    l0bs<<<32768, 256, 0, stream>>>(inputs, ln0w, ln0b, sums, xgs);

    for (int it = 0; it < 3; it++) {
        kq<<<64, 256, 0, stream>>>(slots, ln1w, ln1b, qWT + it * 65536, qb + it * 256,
                                   kW + it * 65536, kb + it * 256, qkf, qkb, denom);
        katt<<<1024, 256, 0, stream>>>(xgs, qkf, qkb, denom, partials);
        kred2<<<256, 256, 0, stream>>>(partials, denom, vWT + it * 65536, vb + it * 256, slots);
        kfin1<<<256, 256, 0, stream>>>(slots, ln2w, ln2b, m1WT + it * 131072, m1b + it * 512, htmp);
        kfin2<<<256, 256, 0, stream>>>(htmp, m2WT + it * 131072, m2b + it * 256, slots,
                                       (float*)d_out, it == 2 ? 1 : 0);
    }
}